// Round 1
// baseline (95.147 us; speedup 1.0000x reference)
//
#include <hip/hip_runtime.h>
#include <math.h>

constexpr int H  = 4096;
constexpr int H2 = 8192;

__global__ __launch_bounds__(256, 4)
void lstm_step_kernel(const float* __restrict__ h_prev,
                      const float* __restrict__ c_prev,
                      const float* __restrict__ x_t,
                      const float* __restrict__ W_f, const float* __restrict__ b_f,
                      const float* __restrict__ W_i, const float* __restrict__ b_i,
                      const float* __restrict__ W_C, const float* __restrict__ b_C,
                      const float* __restrict__ W_o, const float* __restrict__ b_o,
                      float* __restrict__ out)
{
    const int gtid = blockIdx.x * blockDim.x + threadIdx.x;
    const int row  = gtid >> 6;            // one wave64 per output row
    const int lane = threadIdx.x & 63;
    if (row >= H) return;

    const float4* wf = (const float4*)(W_f + (size_t)row * H2);
    const float4* wi = (const float4*)(W_i + (size_t)row * H2);
    const float4* wc = (const float4*)(W_C + (size_t)row * H2);
    const float4* wo = (const float4*)(W_o + (size_t)row * H2);
    const float4* hv = (const float4*)h_prev;
    const float4* xv = (const float4*)x_t;
    const float4* cv = (const float4*)c_prev;

    float4 af = make_float4(0.f, 0.f, 0.f, 0.f);
    float4 ai = make_float4(0.f, 0.f, 0.f, 0.f);
    float4 ac = make_float4(0.f, 0.f, 0.f, 0.f);
    float4 ao = make_float4(0.f, 0.f, 0.f, 0.f);

    // --- first half: columns [0, H) -> z = h_prev for ALL four gates ---
    #pragma unroll 4
    for (int it = 0; it < 16; ++it) {
        const int c = it * 64 + lane;      // float4 index within half, 0..1023
        const float4 z = hv[c];
        const float4 a = wf[c];
        const float4 b = wi[c];
        const float4 d = wc[c];
        const float4 e = wo[c];
        af.x = fmaf(a.x, z.x, af.x); af.y = fmaf(a.y, z.y, af.y);
        af.z = fmaf(a.z, z.z, af.z); af.w = fmaf(a.w, z.w, af.w);
        ai.x = fmaf(b.x, z.x, ai.x); ai.y = fmaf(b.y, z.y, ai.y);
        ai.z = fmaf(b.z, z.z, ai.z); ai.w = fmaf(b.w, z.w, ai.w);
        ac.x = fmaf(d.x, z.x, ac.x); ac.y = fmaf(d.y, z.y, ac.y);
        ac.z = fmaf(d.z, z.z, ac.z); ac.w = fmaf(d.w, z.w, ac.w);
        ao.x = fmaf(e.x, z.x, ao.x); ao.y = fmaf(e.y, z.y, ao.y);
        ao.z = fmaf(e.z, z.z, ao.z); ao.w = fmaf(e.w, z.w, ao.w);
    }

    // --- second half: columns [H, 2H) -> z = x_t for f,i,o ; z = c_prev for C ---
    #pragma unroll 4
    for (int it = 0; it < 16; ++it) {
        const int c  = it * 64 + lane;     // 0..1023
        const int wc4 = 1024 + c;          // float4 index within full row
        const float4 zx = xv[c];
        const float4 zc = cv[c];
        const float4 a = wf[wc4];
        const float4 b = wi[wc4];
        const float4 d = wc[wc4];
        const float4 e = wo[wc4];
        af.x = fmaf(a.x, zx.x, af.x); af.y = fmaf(a.y, zx.y, af.y);
        af.z = fmaf(a.z, zx.z, af.z); af.w = fmaf(a.w, zx.w, af.w);
        ai.x = fmaf(b.x, zx.x, ai.x); ai.y = fmaf(b.y, zx.y, ai.y);
        ai.z = fmaf(b.z, zx.z, ai.z); ai.w = fmaf(b.w, zx.w, ai.w);
        ac.x = fmaf(d.x, zc.x, ac.x); ac.y = fmaf(d.y, zc.y, ac.y);
        ac.z = fmaf(d.z, zc.z, ac.z); ac.w = fmaf(d.w, zc.w, ac.w);
        ao.x = fmaf(e.x, zx.x, ao.x); ao.y = fmaf(e.y, zx.y, ao.y);
        ao.z = fmaf(e.z, zx.z, ao.z); ao.w = fmaf(e.w, zx.w, ao.w);
    }

    float sf = (af.x + af.y) + (af.z + af.w);
    float si = (ai.x + ai.y) + (ai.z + ai.w);
    float sc = (ac.x + ac.y) + (ac.z + ac.w);
    float so = (ao.x + ao.y) + (ao.z + ao.w);

    #pragma unroll
    for (int off = 32; off > 0; off >>= 1) {
        sf += __shfl_down(sf, off, 64);
        si += __shfl_down(si, off, 64);
        sc += __shfl_down(sc, off, 64);
        so += __shfl_down(so, off, 64);
    }

    if (lane == 0) {
        const float f      = 1.f / (1.f + expf(-(sf + b_f[row])));
        const float ig     = 1.f / (1.f + expf(-(si + b_i[row])));
        const float ctilde = tanhf(sc + b_C[row]);
        const float og     = 1.f / (1.f + expf(-(so + b_o[row])));
        const float Cnew   = f * c_prev[row] + ig * ctilde;
        out[row]     = og * tanhf(Cnew);   // h_t
        out[H + row] = Cnew;               // C_t
    }
}

extern "C" void kernel_launch(void* const* d_in, const int* in_sizes, int n_in,
                              void* d_out, int out_size, void* d_ws, size_t ws_size,
                              hipStream_t stream) {
    const float* h_prev = (const float*)d_in[0];
    const float* c_prev = (const float*)d_in[1];
    const float* x_t    = (const float*)d_in[2];
    const float* W_f    = (const float*)d_in[3];
    const float* b_f    = (const float*)d_in[4];
    const float* W_i    = (const float*)d_in[5];
    const float* b_i    = (const float*)d_in[6];
    const float* W_C    = (const float*)d_in[7];
    const float* b_C    = (const float*)d_in[8];
    const float* W_o    = (const float*)d_in[9];
    const float* b_o    = (const float*)d_in[10];
    float* out = (float*)d_out;

    const int waves_needed = H;                       // one wave per row
    const int threads = 256;
    const int blocks  = (waves_needed * 64) / threads; // 1024
    lstm_step_kernel<<<blocks, threads, 0, stream>>>(
        h_prev, c_prev, x_t, W_f, b_f, W_i, b_i, W_C, b_C, W_o, b_o, out);
}